// Round 7
// baseline (101.402 us; speedup 1.0000x reference)
//
#include <hip/hip_runtime.h>
#include <stdint.h>

// PoissonNeuronTransform — bit-exact vs the harness's NUMPY reference (ref=np).
// Validated (absmax 0.0, R11-R18): threefry2x32 partitionable bits, uniform
// bit-trick, fdlibm log1pf port (dead c-branch removed, proof R17), +0.002f,
// sequential f32 cumsum, early exit (monotone RN-fadd), wave-internal ballot
// lane-refill, LPT (descending-rate) handout.
// R19: hoisted per-element f64 reciprocal into setup (LDS).
// R21/22: kEPW=256 (1024 blocks) straggler amortization. 62.5->59.3us.
// R23: 2-eval unroll (per-lane ILP). 59.3->57.4us.
// R24: Markstein CR division by rate (f64 out of the loop). 57.4->58.7 —
//   mixed latency/issue-bound; serial fma chain lengthened critical path.
// R25: Markstein division inside log1pf (vcc-free, kills div_scale/div_fmas
//   vcc serialization between the two ILP chains). 58.7->53.4us, absmax 0.
// R26 (perf only, THIS ROUND): 6 waves/SIMD residency.
//   VALUBusy 82% + OccupancyPercent 26% (~2.1 waves/SIMD time-avg vs 4
//   resident) => issue gaps from dep-chain stalls + block-completion tail
//   (4 blocks/CU, no backfill). Per-eval critical path ~350cyc vs ~700cyc
//   issue per wave-round: 4 waves/SIMD is marginal cover, 6 is ~2x. Pool
//   floor from the R21 straggler lesson: ~30 evals = 15 pair-rounds; at
//   kEPW=171 ideal ~14.6 rounds ~= straggler 15 -> util ~97%. Config:
//   1536 blocks (6144 waves), non-uniform pools — waves [0,4096): 171
//   elems, waves [4096,6144): 170; base = 170*wid + min(wid,4096).
//   Per-element math depends only on the global index o (preserved) ->
//   bit-exact by construction.

static constexpr int      kSpikes = 100;              // NUM_SPIKES
static constexpr int      kBlocks = 1536;             // x256 thr = 6144 waves
static constexpr uint32_t kMaxEPW = 176;              // LDS row (>=171, pad)

__device__ __forceinline__ uint32_t rotl32(uint32_t v, uint32_t d) {
  return (v << d) | (v >> (32u - d));
}

// threefry2x32 with key (0, 42) — matches jax.random.key(42).
__device__ __forceinline__ void threefry2x32_0_42(uint32_t x0, uint32_t x1,
                                                  uint32_t& o0, uint32_t& o1) {
  const uint32_t ks0 = 0u;
  const uint32_t ks1 = 42u;
  const uint32_t ks2 = 0x1BD11BDAu ^ 0u ^ 42u;
  uint32_t a = x0 + ks0;
  uint32_t b = x1 + ks1;
#define TF_ROUND(r) { a += b; b = rotl32(b, (r)); b ^= a; }
  TF_ROUND(13u) TF_ROUND(15u) TF_ROUND(26u) TF_ROUND(6u)
  a += ks1; b += ks2 + 1u;
  TF_ROUND(17u) TF_ROUND(29u) TF_ROUND(16u) TF_ROUND(24u)
  a += ks2; b += ks0 + 2u;
  TF_ROUND(13u) TF_ROUND(15u) TF_ROUND(26u) TF_ROUND(6u)
  a += ks0; b += ks1 + 3u;
  TF_ROUND(17u) TF_ROUND(29u) TF_ROUND(16u) TF_ROUND(24u)
  a += ks1; b += ks2 + 4u;
  TF_ROUND(13u) TF_ROUND(15u) TF_ROUND(26u) TF_ROUND(6u)
  a += ks2; b += ks0 + 5u;
#undef TF_ROUND
  o0 = a; o1 = b;
}

// Branchless fdlibm s_log1pf for x = -m*2^-23, m in [0, 2^23) — bit-exact
// (R12 port; c-branch removed, proof R17; R25 vcc-free Markstein division,
// CR over the live domain: den in [1.707,2.414] normal; quotient consumed
// only when |ff| >= 2^-15 — smaller |x| overridden by tiny-path selects).
__device__ __forceinline__ float fdlibm_log1pf_nb(float x) {
#pragma clang fp contract(off)
  const float ln2_hi = __uint_as_float(0x3f317180u);
  const float ln2_lo = __uint_as_float(0x3717f7d1u);
  const float Lp1 = __uint_as_float(0x3F2AAAABu);
  const float Lp2 = __uint_as_float(0x3ECCCCCDu);
  const float Lp3 = __uint_as_float(0x3E924925u);
  const float Lp4 = __uint_as_float(0x3E638E29u);
  const float Lp5 = __uint_as_float(0x3E3A3325u);
  const float Lp6 = __uint_as_float(0x3E1CD04Fu);
  const float Lp7 = __uint_as_float(0x3E178897u);

  uint32_t hx = __float_as_uint(x);
  uint32_t ax = hx & 0x7fffffffu;

  float u = 1.0f + x;
  uint32_t hu = __float_as_uint(u);
  int k = (int)(hu >> 23) - 127;
  uint32_t m = hu & 0x007fffffu;
  bool half = (m >= 0x3504f7u);
  int k2 = half ? (k + 1) : k;
  float u2 = __uint_as_float(m | (half ? 0x3f000000u : 0x3f800000u));
  float f2 = u2 - 1.0f;

  bool cond0 = ((int32_t)hx <= (int32_t)0xbe95f61fu);
  float kf = cond0 ? 0.0f : (float)k2;
  float ff = cond0 ? x : f2;

  float hfsq = (0.5f * ff) * ff;
  // Markstein division s = RN(ff / (2+ff)), vcc-free (R25):
  float den = 2.0f + ff;
  float y0 = __builtin_amdgcn_rcpf(den);   // v_rcp_f32, <=1 ulp
  float e  = fmaf(-den, y0, 1.0f);         // exact-fma residual
  float y1 = fmaf(y0, e, y0);              // reciprocal err ~2^-25
  float q0 = ff * y1;
  float r1 = fmaf(-den, q0, ff);           // exact residual
  float s  = fmaf(r1, y1, q0);             // == RN(ff/den), Markstein
  float z = s * s;
  float R = z * (Lp1 + z * (Lp2 + z * (Lp3 + z * (Lp4 +
            z * (Lp5 + z * (Lp6 + z * Lp7))))));
  float lowsum = s * (hfsq + R) + kf * ln2_lo;
  float res = kf * ln2_hi - ((hfsq - lowsum) - ff);

  float tiny2 = x - (x * x) * 0.5f;
  res = (ax < 0x38000000u) ? ((ax < 0x33800000u) ? x : tiny2) : res;
  return res;
}

// One spike-interval delta for counter jc: bits -> uniform -> exponential
// -> / rate via Markstein CR division (rt = rate, ry = RN(1/rt)) -> + 0.002.
__device__ __forceinline__ float spike_delta(uint32_t jc, float rt, float ry) {
#pragma clang fp contract(off)
  uint32_t b1, b2;
  threefry2x32_0_42(0u, jc, b1, b2);
  uint32_t bits = b1 ^ b2;
  float uu = __uint_as_float((bits >> 9) | 0x3f800000u) - 1.0f;  // [0, 1)
  float expo = -fdlibm_log1pf_nb(-uu);
  float q0 = expo * ry;
  float rr = fmaf(-rt, q0, expo);          // exact residual (fma)
  float q  = fmaf(rr, ry, q0);             // == RN(expo/rt)
  return q + 0.002f;
}

__global__ void __launch_bounds__(256) poisson_count_kernel(
    const float* __restrict__ rates, int* __restrict__ out) {
#pragma clang fp contract(off)
  __shared__ uint32_t pool_idx[4][kMaxEPW];  // local element idx (LPT order)
  __shared__ float2   pool_ry[4][kMaxEPW];   // {rate, RN(1/rate)}
  int wslot = (int)threadIdx.x >> 6;
  int lane  = (int)threadIdx.x & 63;
  uint32_t wid = (uint32_t)blockIdx.x * 4u + (uint32_t)wslot;
  // Non-uniform pools: waves [0,4096) own 171 elements, rest own 170.
  uint32_t epw  = (wid < 4096u) ? 171u : 170u;
  uint32_t base = 170u * wid + (wid < 4096u ? wid : 4096u);
  uint64_t lmask_lt = (1ull << lane) - 1ull;

  // ---- one-time setup: LPT buckets + hoisted CR f32 reciprocals ----
  {
    float r[3];
    int   bb[3];
    bool  val[3];
    uint32_t pos[3];
#pragma unroll
    for (int i = 0; i < 3; ++i) {
      uint32_t idx = (uint32_t)(i * 64) + (uint32_t)lane;
      val[i] = idx < epw;
      r[i] = val[i] ? rates[base + idx] : 1.0f;
      int q = (int)(r[i] * 0.4f);
      q = q > 7 ? 7 : q;
      bb[i] = val[i] ? (7 - q) : 100;      // 100 = invalid sentinel
    }
    uint32_t off = 0;
#pragma unroll
    for (int b = 0; b < 8; ++b) {
      uint64_t m0 = __ballot(bb[0] == b);
      uint64_t m1 = __ballot(bb[1] == b);
      uint64_t m2 = __ballot(bb[2] == b);
      uint32_t c0 = (uint32_t)__popcll(m0);
      uint32_t c1 = (uint32_t)__popcll(m1);
      if (bb[0] == b) pos[0] = off + (uint32_t)__popcll(m0 & lmask_lt);
      if (bb[1] == b) pos[1] = off + c0 + (uint32_t)__popcll(m1 & lmask_lt);
      if (bb[2] == b) pos[2] = off + c0 + c1 + (uint32_t)__popcll(m2 & lmask_lt);
      off += c0 + c1 + (uint32_t)__popcll(m2);
    }
#pragma unroll
    for (int i = 0; i < 3; ++i) {
      if (val[i]) {
        pool_idx[wslot][pos[i]] = (uint32_t)(i * 64) + (uint32_t)lane;
        // CR f32 reciprocal via f64 (setup-only f64; none in the main loop)
        pool_ry[wslot][pos[i]] = make_float2(r[i], (float)(1.0 / (double)r[i]));
      }
    }
  }
  __syncthreads();

  // ---- main loop: ballot lane-refill; TWO sequential evals per round ----
  uint32_t next = 0;                       // wave-uniform: elements handed out
  uint32_t o = 0;
  uint32_t jc = 0;                         // threefry counter = (s<<20) + o
  float run = 0.0f;
  int s = 0;                               // evals consumed (always even)
  float rt = 1.0f, ry = 1.0f;              // rate, RN(1/rate)
  bool active = false;

  while (true) {
    uint64_t needmask = __ballot(!active);
    if (needmask != 0ull) {
      uint32_t avail = epw - next;
      if (avail != 0u) {
        if (!active) {
          uint32_t rank = (uint32_t)__popcll(needmask & lmask_lt);
          if (rank < avail) {
            uint32_t slot = next + rank;
            o = base + pool_idx[wslot][slot];
            float2 ryv = pool_ry[wslot][slot];
            rt = ryv.x; ry = ryv.y;
            run = 0.0f; s = 0; jc = o;     // s=0 -> jc = o
            active = true;
          }
        }
        uint32_t nneed = (uint32_t)__popcll(needmask);
        next += (nneed < avail) ? nneed : avail;
      } else if (needmask == ~0ull) {
        break;                             // pool empty, all lanes idle
      }
    }

    if (active) {
      // Two independent delta pipelines (ILP x2); sequential RN cumsum.
      float d1 = spike_delta(jc, rt, ry);             // eval s
      float d2 = spike_delta(jc + 0x100000u, rt, ry); // eval s+1 (2^20)
      float run1 = run + d1;
      float run2 = run1 + d2;
      s += 2;
      bool lt1 = (run1 < 1.0f);
      bool lt2 = (run2 < 1.0f);
      // monotone: d2 > 0 => (lt2 => lt1); single exit branch.
      if (!lt2 || s == kSpikes) {
        // count: crossed in this pair -> lt1 ? s-1 : s-2; else cap -> 100.
        out[o] = lt2 ? kSpikes : (lt1 ? (s - 1) : (s - 2));
        active = false;
      } else {
        run = run2;
        jc += 0x200000u;                   // += 2*2^20
      }
    }
  }
}

extern "C" void kernel_launch(void* const* d_in, const int* in_sizes, int n_in,
                              void* d_out, int out_size, void* d_ws, size_t ws_size,
                              hipStream_t stream) {
  const float* rates = (const float*)d_in[0];
  int* out = (int*)d_out;
  (void)in_sizes; (void)n_in; (void)out_size; (void)d_ws; (void)ws_size;
  poisson_count_kernel<<<kBlocks, 256, 0, stream>>>(rates, out);
}

// Round 8
// 98.788 us; speedup vs baseline: 1.0265x; 1.0265x over previous
//
#include <hip/hip_runtime.h>
#include <stdint.h>

// PoissonNeuronTransform — bit-exact vs the harness's NUMPY reference (ref=np).
// Validated (absmax 0.0, R11-R18): threefry2x32 partitionable bits, uniform
// bit-trick, fdlibm log1pf port (dead c-branch removed, proof R17), +0.002f,
// sequential f32 cumsum, early exit (monotone RN-fadd), wave-internal ballot
// lane-refill, LPT (descending-rate) handout.
// R19: hoisted per-element f64 reciprocal into setup (LDS).
// R21/22: kEPW=256 (1024 blocks) straggler amortization. 62.5->59.3us.
// R23: 2-eval unroll (per-lane ILP). 59.3->57.4us.
// R24: Markstein CR division by rate (f64 out of the loop). 57.4->58.7.
// R25: Markstein division inside log1pf (vcc-free). 58.7->53.4us, absmax 0.
// R26: 6 waves/SIMD (1536 blocks, non-uniform pools). 53.4->54.7 — REVERTED.
//   Scheduling axis is exhausted: 4w/6w/8w x ILP-1/2 all within +-4%; only
//   instruction cuts have moved wall time (R25: -10% inst -> -9% time).
//   Regime: VALU-throughput-bound at ~3-5 cyc/wave-inst sustained.
// R27 (perf only, THIS ROUND): revert to R25 schedule + rare-path
//   branch-out of the fdlibm tiny selects. uu = m*2^-23 (23 random bits),
//   so ax < 0x38000000 <=> m < 256 <=> P = 2^-15/eval; P(any of 128
//   evals/round) ~ 0.4%. The always-paid 7 inst (2 cmp + 3 tiny2 + 2
//   cndmask) become a wave-uniform __ballot guard (~2 inst); the 0.4% of
//   rounds with a tiny lane run the ORIGINAL select block for all lanes —
//   identical bits on every path -> bit-exact by construction.

static constexpr int      kSpikes = 100;              // NUM_SPIKES
static constexpr int      kBlocks = 1024;             // x256 thr = 4096 waves
static constexpr uint32_t kEPW    = 256;              // elements per wave

__device__ __forceinline__ uint32_t rotl32(uint32_t v, uint32_t d) {
  return (v << d) | (v >> (32u - d));
}

// threefry2x32 with key (0, 42) — matches jax.random.key(42).
__device__ __forceinline__ void threefry2x32_0_42(uint32_t x0, uint32_t x1,
                                                  uint32_t& o0, uint32_t& o1) {
  const uint32_t ks0 = 0u;
  const uint32_t ks1 = 42u;
  const uint32_t ks2 = 0x1BD11BDAu ^ 0u ^ 42u;
  uint32_t a = x0 + ks0;
  uint32_t b = x1 + ks1;
#define TF_ROUND(r) { a += b; b = rotl32(b, (r)); b ^= a; }
  TF_ROUND(13u) TF_ROUND(15u) TF_ROUND(26u) TF_ROUND(6u)
  a += ks1; b += ks2 + 1u;
  TF_ROUND(17u) TF_ROUND(29u) TF_ROUND(16u) TF_ROUND(24u)
  a += ks2; b += ks0 + 2u;
  TF_ROUND(13u) TF_ROUND(15u) TF_ROUND(26u) TF_ROUND(6u)
  a += ks0; b += ks1 + 3u;
  TF_ROUND(17u) TF_ROUND(29u) TF_ROUND(16u) TF_ROUND(24u)
  a += ks1; b += ks2 + 4u;
  TF_ROUND(13u) TF_ROUND(15u) TF_ROUND(26u) TF_ROUND(6u)
  a += ks2; b += ks0 + 5u;
#undef TF_ROUND
  o0 = a; o1 = b;
}

// Branchless fdlibm s_log1pf for x = -m*2^-23, m in [0, 2^23) — bit-exact
// (R12 port; c-branch removed, proof R17; R25 vcc-free Markstein division;
// R27 tiny-path selects hoisted behind a wave-uniform rare branch).
__device__ __forceinline__ float fdlibm_log1pf_nb(float x) {
#pragma clang fp contract(off)
  const float ln2_hi = __uint_as_float(0x3f317180u);
  const float ln2_lo = __uint_as_float(0x3717f7d1u);
  const float Lp1 = __uint_as_float(0x3F2AAAABu);
  const float Lp2 = __uint_as_float(0x3ECCCCCDu);
  const float Lp3 = __uint_as_float(0x3E924925u);
  const float Lp4 = __uint_as_float(0x3E638E29u);
  const float Lp5 = __uint_as_float(0x3E3A3325u);
  const float Lp6 = __uint_as_float(0x3E1CD04Fu);
  const float Lp7 = __uint_as_float(0x3E178897u);

  uint32_t hx = __float_as_uint(x);
  uint32_t ax = hx & 0x7fffffffu;

  float u = 1.0f + x;
  uint32_t hu = __float_as_uint(u);
  int k = (int)(hu >> 23) - 127;
  uint32_t m = hu & 0x007fffffu;
  bool half = (m >= 0x3504f7u);
  int k2 = half ? (k + 1) : k;
  float u2 = __uint_as_float(m | (half ? 0x3f000000u : 0x3f800000u));
  float f2 = u2 - 1.0f;

  bool cond0 = ((int32_t)hx <= (int32_t)0xbe95f61fu);
  float kf = cond0 ? 0.0f : (float)k2;
  float ff = cond0 ? x : f2;

  float hfsq = (0.5f * ff) * ff;
  // Markstein division s = RN(ff / (2+ff)), vcc-free (R25):
  float den = 2.0f + ff;
  float y0 = __builtin_amdgcn_rcpf(den);   // v_rcp_f32, <=1 ulp
  float e  = fmaf(-den, y0, 1.0f);         // exact-fma residual
  float y1 = fmaf(y0, e, y0);              // reciprocal err ~2^-25
  float q0 = ff * y1;
  float r1 = fmaf(-den, q0, ff);           // exact residual
  float s  = fmaf(r1, y1, q0);             // == RN(ff/den), Markstein
  float z = s * s;
  float R = z * (Lp1 + z * (Lp2 + z * (Lp3 + z * (Lp4 +
            z * (Lp5 + z * (Lp6 + z * Lp7))))));
  float lowsum = s * (hfsq + R) + kf * ln2_lo;
  float res = kf * ln2_hi - ((hfsq - lowsum) - ff);

  // R27: tiny path (|x| < 2^-15 <=> 23-bit m < 256, P = 2^-15/eval) taken
  // behind a wave-uniform rare branch; selects identical to the original.
  if (__builtin_expect(__ballot(ax < 0x38000000u) != 0ull, 0)) {
    float tiny2 = x - (x * x) * 0.5f;
    res = (ax < 0x38000000u) ? ((ax < 0x33800000u) ? x : tiny2) : res;
  }
  return res;
}

// One spike-interval delta for counter jc: bits -> uniform -> exponential
// -> / rate via Markstein CR division (rt = rate, ry = RN(1/rt)) -> + 0.002.
__device__ __forceinline__ float spike_delta(uint32_t jc, float rt, float ry) {
#pragma clang fp contract(off)
  uint32_t b1, b2;
  threefry2x32_0_42(0u, jc, b1, b2);
  uint32_t bits = b1 ^ b2;
  float uu = __uint_as_float((bits >> 9) | 0x3f800000u) - 1.0f;  // [0, 1)
  float expo = -fdlibm_log1pf_nb(-uu);
  float q0 = expo * ry;
  float rr = fmaf(-rt, q0, expo);          // exact residual (fma)
  float q  = fmaf(rr, ry, q0);             // == RN(expo/rt)
  return q + 0.002f;
}

__global__ void __launch_bounds__(256) poisson_count_kernel(
    const float* __restrict__ rates, int* __restrict__ out) {
#pragma clang fp contract(off)
  __shared__ uint32_t pool_idx[4][kEPW];   // local element index (LPT order)
  __shared__ float2   pool_ry[4][kEPW];    // {rate, RN(1/rate)} per element
  int wslot = (int)threadIdx.x >> 6;
  int lane  = (int)threadIdx.x & 63;
  int wid   = blockIdx.x * 4 + wslot;
  uint32_t base = (uint32_t)wid * kEPW;
  uint64_t lmask_lt = (1ull << lane) - 1ull;

  // ---- one-time setup: LPT buckets + hoisted CR f32 reciprocals ----
  {
    float r[4];
    int   bb[4];
    uint32_t pos[4];
#pragma unroll
    for (int i = 0; i < 4; ++i) {
      r[i] = rates[base + (uint32_t)(i * 64) + (uint32_t)lane];
      int q = (int)(r[i] * 0.4f);
      q = q > 7 ? 7 : q;
      bb[i] = 7 - q;                       // bucket 0 = highest rates
    }
    uint32_t off = 0;
#pragma unroll
    for (int b = 0; b < 8; ++b) {
      uint64_t m0 = __ballot(bb[0] == b);
      uint64_t m1 = __ballot(bb[1] == b);
      uint64_t m2 = __ballot(bb[2] == b);
      uint64_t m3 = __ballot(bb[3] == b);
      uint32_t c0 = (uint32_t)__popcll(m0);
      uint32_t c1 = (uint32_t)__popcll(m1);
      uint32_t c2 = (uint32_t)__popcll(m2);
      uint32_t c3 = (uint32_t)__popcll(m3);
      if (bb[0] == b) pos[0] = off + (uint32_t)__popcll(m0 & lmask_lt);
      if (bb[1] == b) pos[1] = off + c0 + (uint32_t)__popcll(m1 & lmask_lt);
      if (bb[2] == b) pos[2] = off + c0 + c1 + (uint32_t)__popcll(m2 & lmask_lt);
      if (bb[3] == b) pos[3] = off + c0 + c1 + c2 + (uint32_t)__popcll(m3 & lmask_lt);
      off += c0 + c1 + c2 + c3;
    }
#pragma unroll
    for (int i = 0; i < 4; ++i) {
      pool_idx[wslot][pos[i]] = (uint32_t)(i * 64) + (uint32_t)lane;
      // CR f32 reciprocal via f64 (setup-only f64; none in the main loop)
      pool_ry[wslot][pos[i]] = make_float2(r[i], (float)(1.0 / (double)r[i]));
    }
  }
  __syncthreads();

  // ---- main loop: ballot lane-refill; TWO sequential evals per round ----
  uint32_t next = 0;                       // wave-uniform: elements handed out
  uint32_t o = 0;
  uint32_t jc = 0;                         // threefry counter = (s<<20) + o
  float run = 0.0f;
  int s = 0;                               // evals consumed (always even)
  float rt = 1.0f, ry = 1.0f;              // rate, RN(1/rate)
  bool active = false;

  while (true) {
    uint64_t needmask = __ballot(!active);
    if (needmask != 0ull) {
      uint32_t avail = kEPW - next;
      if (avail != 0u) {
        if (!active) {
          uint32_t rank = (uint32_t)__popcll(needmask & lmask_lt);
          if (rank < avail) {
            uint32_t slot = next + rank;
            o = base + pool_idx[wslot][slot];
            float2 ryv = pool_ry[wslot][slot];
            rt = ryv.x; ry = ryv.y;
            run = 0.0f; s = 0; jc = o;     // s=0 -> jc = o
            active = true;
          }
        }
        uint32_t nneed = (uint32_t)__popcll(needmask);
        next += (nneed < avail) ? nneed : avail;
      } else if (needmask == ~0ull) {
        break;                             // pool empty, all lanes idle
      }
    }

    if (active) {
      // Two independent delta pipelines (ILP x2); sequential RN cumsum.
      float d1 = spike_delta(jc, rt, ry);             // eval s
      float d2 = spike_delta(jc + 0x100000u, rt, ry); // eval s+1 (2^20)
      float run1 = run + d1;
      float run2 = run1 + d2;
      s += 2;
      bool lt1 = (run1 < 1.0f);
      bool lt2 = (run2 < 1.0f);
      // monotone: d2 > 0 => (lt2 => lt1); single exit branch.
      if (!lt2 || s == kSpikes) {
        // count: crossed in this pair -> lt1 ? s-1 : s-2; else cap -> 100.
        out[o] = lt2 ? kSpikes : (lt1 ? (s - 1) : (s - 2));
        active = false;
      } else {
        run = run2;
        jc += 0x200000u;                   // += 2*2^20
      }
    }
  }
}

extern "C" void kernel_launch(void* const* d_in, const int* in_sizes, int n_in,
                              void* d_out, int out_size, void* d_ws, size_t ws_size,
                              hipStream_t stream) {
  const float* rates = (const float*)d_in[0];
  int* out = (int*)d_out;
  (void)in_sizes; (void)n_in; (void)out_size; (void)d_ws; (void)ws_size;
  poisson_count_kernel<<<kBlocks, 256, 0, stream>>>(rates, out);
}